// Round 2
// baseline (667.091 us; speedup 1.0000x reference)
//
#include <hip/hip_runtime.h>
#include <hip/hip_cooperative_groups.h>

namespace cg = cooperative_groups;

#define NN 8192
#define NBLK 1024
#define ROWS_PER_BLOCK (NN / NBLK)     // 8 rows/block, 2 per wave
#define CHUNKS 128
#define CHUNK_ROWS (NN / CHUNKS)       // 64 rows per column-pass chunk
#define COLTILES 8                     // 8 tiles x 1024 cols

// ws layout (floats): w[NN] | diag[NN] | partial[CHUNKS*NN]  (~4.1 MB)

__global__ void __launch_bounds__(256, 4)
fused(const float* __restrict__ ts,
      const float* __restrict__ state,
      const float* __restrict__ betas,
      const float* __restrict__ deltas,
      const float* __restrict__ cs,
      const float* __restrict__ ps,
      float* __restrict__ w,
      float* __restrict__ diag,
      float* __restrict__ partial,
      float* __restrict__ out)
{
    cg::grid_group grid = cg::this_grid();
    const int tid  = threadIdx.x;
    const int lane = tid & 63;
    const int wid  = tid >> 6;

    // ---- Phase 1: per-row sum of squares -> w[i] = norm*V, diag[i] ----
    {
        const int rowBase = blockIdx.x * ROWS_PER_BLOCK + wid * 2;
        for (int r = 0; r < 2; ++r) {
            const int row = rowBase + r;
            const float4* rp = reinterpret_cast<const float4*>(ts + (size_t)row * NN);
            float sum = 0.f;
            #pragma unroll 8
            for (int k = lane; k < NN / 4; k += 64) {
                float4 v = rp[k];
                sum += v.x * v.x + v.y * v.y + v.z * v.z + v.w * v.w;
            }
            #pragma unroll
            for (int off = 32; off; off >>= 1) sum += __shfl_down(sum, off);
            if (lane == 0) {
                float d = ts[(size_t)row * NN + row];
                d = d * d;
                const float norm = fminf(d / (sum - d), 1.0f);
                w[row]    = norm * state[3 * row + 2];
                diag[row] = d;
            }
        }
    }
    grid.sync();

    // ---- Phase 2: weighted partial column sums ----
    {
        __shared__ float wsm[CHUNK_ROWS];
        const int bx   = blockIdx.x & (COLTILES - 1);   // column tile
        const int by   = blockIdx.x >> 3;               // row chunk 0..127
        const int row0 = by * CHUNK_ROWS;
        if (tid < CHUNK_ROWS) wsm[tid] = w[row0 + tid];
        __syncthreads();

        const int col = bx * 1024 + tid * 4;
        const float* base = ts + (size_t)row0 * NN + col;
        float4 acc = {0.f, 0.f, 0.f, 0.f};
        #pragma unroll 4
        for (int r = 0; r < CHUNK_ROWS; ++r) {
            const float wi = wsm[r];                    // LDS broadcast
            float4 v = *reinterpret_cast<const float4*>(base + (size_t)r * NN);
            acc.x += wi * v.x * v.x;
            acc.y += wi * v.y * v.y;
            acc.z += wi * v.z * v.z;
            acc.w += wi * v.w * v.w;
        }
        *reinterpret_cast<float4*>(partial + (size_t)by * NN + col) = acc;
    }
    grid.sync();

    // ---- Phase 3: reduce partials + O(N) elementwise, blocks 0..31 ----
    if (blockIdx.x < NN / 256) {
        const int j = blockIdx.x * 256 + tid;
        float coup = 0.f;
        #pragma unroll 8
        for (int c = 0; c < CHUNKS; ++c) coup += partial[(size_t)c * NN + j];
        const float dj = diag[j];
        coup -= w[j] * dj;                              // remove i==j term

        const float U = state[3 * j + 0];
        const float I = state[3 * j + 1];
        const float V = state[3 * j + 2];
        const float b2 = betas[j] * betas[j];
        const float d2 = deltas[j] * deltas[j];
        const float p2 = ps[j] * ps[j];
        const float c2 = cs[j] * cs[j];
        const float bUV = b2 * U * V;

        out[3 * j + 0] = -bUV;
        out[3 * j + 1] = bUV - d2 * I;
        out[3 * j + 2] = p2 * I - c2 * V - dj + coup;
    }
}

extern "C" void kernel_launch(void* const* d_in, const int* in_sizes, int n_in,
                              void* d_out, int out_size, void* d_ws, size_t ws_size,
                              hipStream_t stream) {
    // inputs: 0:t 1:state 2:betas 3:deltas 4:cs 5:ps 6:ts
    const float* state  = (const float*)d_in[1];
    const float* betas  = (const float*)d_in[2];
    const float* deltas = (const float*)d_in[3];
    const float* cs     = (const float*)d_in[4];
    const float* ps     = (const float*)d_in[5];
    const float* ts     = (const float*)d_in[6];
    float* out = (float*)d_out;

    float* w       = (float*)d_ws;
    float* diag    = w + NN;
    float* partial = diag + NN;

    void* args[] = { (void*)&ts, (void*)&state, (void*)&betas, (void*)&deltas,
                     (void*)&cs, (void*)&ps, (void*)&w, (void*)&diag,
                     (void*)&partial, (void*)&out };
    hipLaunchCooperativeKernel((const void*)fused, dim3(NBLK), dim3(256),
                               args, 0, stream);
}

// Round 3
// 416.090 us; speedup vs baseline: 1.6032x; 1.6032x over previous
//
#include <hip/hip_runtime.h>

#define NN 8192
#define CHUNKS 128
#define CHUNK_ROWS (NN / CHUNKS)   // 64 rows per column-pass chunk
#define COLTILES 8                 // 8 tiles x 1024 cols

// ws layout (floats): w[NN] | diag[NN] | partial[CHUNKS*NN]  (~4.3 MB)

// --- K1: per-row sum of squares -> w[i] = norm*V, diag[i] ------------------
__global__ void __launch_bounds__(256)
row_pass(const float* __restrict__ ts,
         const float* __restrict__ state,
         float* __restrict__ w,
         float* __restrict__ diag_out) {
    const int row = blockIdx.x;
    const float4* rowp = reinterpret_cast<const float4*>(ts + (size_t)row * NN);
    float sum = 0.f;
    #pragma unroll
    for (int k = threadIdx.x; k < NN / 4; k += 256) {   // 8 iters, independent
        float4 v = rowp[k];
        sum += v.x * v.x + v.y * v.y + v.z * v.z + v.w * v.w;
    }
    #pragma unroll
    for (int off = 32; off; off >>= 1) sum += __shfl_down(sum, off);
    __shared__ float red[4];
    const int lane = threadIdx.x & 63;
    const int wid  = threadIdx.x >> 6;
    if (lane == 0) red[wid] = sum;
    __syncthreads();
    if (threadIdx.x == 0) {
        float total = red[0] + red[1] + red[2] + red[3];
        float d = ts[(size_t)row * NN + row];
        d = d * d;
        const float norm = fminf(d / (total - d), 1.0f);
        w[row]        = norm * state[3 * row + 2];
        diag_out[row] = d;
    }
}

// --- K2: partial weighted column sums --------------------------------------
// blockIdx.x: column tile (256 threads x float4 = 1024 cols)
// blockIdx.y: row chunk of CHUNK_ROWS rows
__global__ void __launch_bounds__(256)
col_pass(const float* __restrict__ ts,
         const float* __restrict__ w,
         float* __restrict__ partial) {
    __shared__ float wsm[CHUNK_ROWS];
    const int row0 = blockIdx.y * CHUNK_ROWS;
    if (threadIdx.x < CHUNK_ROWS) wsm[threadIdx.x] = w[row0 + threadIdx.x];
    __syncthreads();

    const int col = blockIdx.x * 1024 + threadIdx.x * 4;
    const float* base = ts + (size_t)row0 * NN + col;
    float4 acc = {0.f, 0.f, 0.f, 0.f};
    #pragma unroll 8
    for (int r = 0; r < CHUNK_ROWS; ++r) {
        const float wi = wsm[r];                        // LDS broadcast
        float4 v = *reinterpret_cast<const float4*>(base + (size_t)r * NN);
        acc.x += wi * v.x * v.x;
        acc.y += wi * v.y * v.y;
        acc.z += wi * v.z * v.z;
        acc.w += wi * v.w * v.w;
    }
    *reinterpret_cast<float4*>(partial + (size_t)blockIdx.y * NN + col) = acc;
}

// --- K3: reduce partials + O(N) elementwise --------------------------------
__global__ void __launch_bounds__(256)
finalize(const float* __restrict__ state,
         const float* __restrict__ betas,
         const float* __restrict__ deltas,
         const float* __restrict__ cs,
         const float* __restrict__ ps,
         const float* __restrict__ w,
         const float* __restrict__ diag,
         const float* __restrict__ partial,
         float* __restrict__ out) {
    const int j = blockIdx.x * 256 + threadIdx.x;
    float coup = 0.f;
    #pragma unroll 8
    for (int c = 0; c < CHUNKS; ++c) coup += partial[(size_t)c * NN + j];
    const float dj = diag[j];
    coup -= w[j] * dj;                                  // remove i==j term

    const float U = state[3 * j + 0];
    const float I = state[3 * j + 1];
    const float V = state[3 * j + 2];
    const float b2 = betas[j] * betas[j];
    const float d2 = deltas[j] * deltas[j];
    const float p2 = ps[j] * ps[j];
    const float c2 = cs[j] * cs[j];
    const float bUV = b2 * U * V;

    out[3 * j + 0] = -bUV;
    out[3 * j + 1] = bUV - d2 * I;
    out[3 * j + 2] = p2 * I - c2 * V - dj + coup;
}

extern "C" void kernel_launch(void* const* d_in, const int* in_sizes, int n_in,
                              void* d_out, int out_size, void* d_ws, size_t ws_size,
                              hipStream_t stream) {
    // inputs: 0:t 1:state 2:betas 3:deltas 4:cs 5:ps 6:ts
    const float* state  = (const float*)d_in[1];
    const float* betas  = (const float*)d_in[2];
    const float* deltas = (const float*)d_in[3];
    const float* cs     = (const float*)d_in[4];
    const float* ps     = (const float*)d_in[5];
    const float* ts     = (const float*)d_in[6];
    float* out = (float*)d_out;

    float* w       = (float*)d_ws;
    float* diag    = w + NN;
    float* partial = diag + NN;

    row_pass<<<NN, 256, 0, stream>>>(ts, state, w, diag);

    dim3 g2(COLTILES, CHUNKS);
    col_pass<<<g2, 256, 0, stream>>>(ts, w, partial);

    finalize<<<NN / 256, 256, 0, stream>>>(state, betas, deltas, cs, ps,
                                           w, diag, partial, out);
}